// Round 15
// baseline (89.458 us; speedup 1.0000x reference)
//
#include <hip/hip_runtime.h>

// MaskedDenseMatMul: out[b,h,q,k] = (sum_d a[b,h,q,d]*b[b,h,k,d]) * mask[b,0,q,k]
// B=2 H=8 S=2048 D=64, fp32 in/out.  Memory-bound on the 256 MiB output write.
//
// R15 design — max-occupancy store duty cycle (the 3x-confirmed lever pushed
// to its limit):
//  R12 anchor (79.5us) runs 16 waves/CU (VGPR ~130).  The fill kernel's
//  7 TB/s regime = "some wave is always issuing stores".  Here per-wave state
//  shrinks to <=64 VGPR -> __launch_bounds__(256,8) -> 8 waves/SIMD = 32/CU:
//   - wave = 32 cols x 256 rows (16 iters); B frags loop-invariant (16 VGPR)
//   - A bf16 + mask u8 staging at depth 2: with 8 waves/SIMD, TLP covers the
//     load latency (R11's depth-2 failure was at 4 waves/SIMD, prefetch-only)
//   - store-last discipline unchanged: MFMA -> select -> prefetch(n+2) ->
//     2 nt stores; stores always youngest vmem ops, never drained
//   - 8192 waves = 2048 blocks = EXACTLY one full-occupancy round (8 blk/CU)
//   - consecutive blocks = adjacent 32-col panels of one (ro,bh): dense
//     concurrent write band (R14's swizzle broke this -> reverted)
//  Fused prep (bf16 cvt + u8 mask pack) unchanged from R12.

typedef __attribute__((ext_vector_type(8))) short bf16x8;
typedef __attribute__((ext_vector_type(4))) float f32x4;
typedef __attribute__((ext_vector_type(2))) unsigned int u32x2;

static constexpr int S = 2048;
static constexpr int D = 64;
static constexpr size_t NELEM = (size_t)16 * S * D;   // elems per A/B input
static constexpr size_t NMASK = (size_t)2 * S * S;    // mask elems (B*S*S)

__device__ inline short f2bf(float f) {
    union { float f; unsigned u; } v; v.f = f;
    unsigned r = (v.u + 0x7FFFu + ((v.u >> 16) & 1u)) >> 16;
    return (short)r;
}

// ------------- fused pre-pass: cvt A (1024 blk), cvt B (1024), pack mask (4096)
__global__ __launch_bounds__(256) void prep_kernel(const float* __restrict__ a,
                                                   const float* __restrict__ b,
                                                   const float* __restrict__ m,
                                                   short* __restrict__ a16,
                                                   short* __restrict__ b16,
                                                   unsigned char* __restrict__ m8) {
    const int blk = blockIdx.x;
    if (blk < 2048) {
        const float* src = (blk < 1024) ? a : b;
        short* dst       = (blk < 1024) ? a16 : b16;
        size_t i = ((size_t)(blk & 1023) * 256 + threadIdx.x) * 8;
        f32x4 f0 = *(const f32x4*)(src + i);
        f32x4 f1 = *(const f32x4*)(src + i + 4);
        bf16x8 t;
        t[0] = f2bf(f0[0]); t[1] = f2bf(f0[1]); t[2] = f2bf(f0[2]); t[3] = f2bf(f0[3]);
        t[4] = f2bf(f1[0]); t[5] = f2bf(f1[1]); t[6] = f2bf(f1[2]); t[7] = f2bf(f1[3]);
        *(bf16x8*)(dst + i) = t;
    } else {
        size_t i = ((size_t)(blk - 2048) * 256 + threadIdx.x) * 8;
        f32x4 f0 = *(const f32x4*)(m + i);
        f32x4 f1 = *(const f32x4*)(m + i + 4);
        unsigned w0 = 0, w1 = 0;
        w0 |= (f0[0] != 0.f ? 1u : 0u);
        w0 |= (f0[1] != 0.f ? 1u : 0u) << 8;
        w0 |= (f0[2] != 0.f ? 1u : 0u) << 16;
        w0 |= (f0[3] != 0.f ? 1u : 0u) << 24;
        w1 |= (f1[0] != 0.f ? 1u : 0u);
        w1 |= (f1[1] != 0.f ? 1u : 0u) << 8;
        w1 |= (f1[2] != 0.f ? 1u : 0u) << 16;
        w1 |= (f1[3] != 0.f ? 1u : 0u) << 24;
        u32x2 w; w[0] = w0; w[1] = w1;
        *(u32x2*)(m8 + i) = w;
    }
}

// ------------- main kernel: 8 waves/SIMD, depth-2 staging, nt stores ---------
__global__ __launch_bounds__(256, 8) void masked_mm_bf16_kernel(
    const short* __restrict__ A16,
    const short* __restrict__ B16,
    const unsigned char* __restrict__ M8,
    float* __restrict__ O) {

    const int lane  = threadIdx.x & 63;
    const int rlane = lane & 15;              // MFMA operand row within 16
    const int kg    = lane >> 4;              // k-group 0..3

    // wave id -> (col panel, row octant, bh); 4 waves of a block share
    // (ro,bh) -> identical A reads (L1/L2 hits), adjacent 32-col panels;
    // consecutive blocks extend the same dense write band
    const int gw = blockIdx.x * 4 + (threadIdx.x >> 6);  // 0..8191
    const int cp = gw & 63;                   // 64 col panels of 32
    const int ro = (gw >> 6) & 7;             // 8 row octants of 256
    const int bh = gw >> 9;                   // 0..15
    const int bb = bh >> 3;

    const int c0 = cp * 32;
    const int r0 = ro * 256;

    const short* __restrict__ Ab = A16 + (size_t)bh * S * D;
    const short* __restrict__ Bb = B16 + (size_t)bh * S * D;
    const unsigned char* __restrict__ Mb = M8 + (size_t)bb * S * S;
    float* __restrict__ Ob       = O + (size_t)bh * S * S;

    // ---- loop-invariant B fragments: 2 tiles x (2 x K=32) = 16 VGPR ----
    bf16x8 bs0[2], bs1[2];
#pragma unroll
    for (int t = 0; t < 2; ++t) {
        const short* pb = Bb + (size_t)(c0 + t * 16 + rlane) * D + kg * 8;
        bs0[t] = *(const bf16x8*)(pb);
        bs1[t] = *(const bf16x8*)(pb + 32);
    }

    // ---- per-lane base pointers (advance by 16 rows per iteration) ----
    const short*         pa0 = Ab + (size_t)(r0 + rlane) * D + kg * 8;
    const unsigned char* pm0 = Mb + (size_t)(r0 + rlane) * S + c0 + kg * 4;
    float*               po0 = Ob + (size_t)(r0 + rlane) * S + c0 + kg * 4;

    // ---- depth-2 register staging (A frags + mask words) ----
    bf16x8   sa0[2], sa1[2];
    unsigned smw[2][2];
#pragma unroll
    for (int n = 0; n < 2; ++n) {
        sa0[n] = *(const bf16x8*)(pa0 + (size_t)n * 16 * D);
        sa1[n] = *(const bf16x8*)(pa0 + (size_t)n * 16 * D + 32);
#pragma unroll
        for (int t = 0; t < 2; ++t)
            smw[n][t] = *(const unsigned*)(pm0 + (size_t)n * 16 * S + t * 16);
    }

    // ---- main loop: 16 row-groups, fully unrolled (static slot indices) ----
#pragma unroll
    for (int n = 0; n < 16; ++n) {
        const int sl = n & 1;

        // MFMA (swapped operands: acc[t][j] = O[r0+n*16+rlane][c0+t*16+kg*4+j])
        f32x4 acc[2];
#pragma unroll
        for (int t = 0; t < 2; ++t) {
            f32x4 z = {0.f, 0.f, 0.f, 0.f};
            z = __builtin_amdgcn_mfma_f32_16x16x32_bf16(bs0[t], sa0[sl], z, 0, 0, 0);
            z = __builtin_amdgcn_mfma_f32_16x16x32_bf16(bs1[t], sa1[sl], z, 0, 0, 0);
            acc[t] = z;
        }

        // mask select (consumes smw[sl] before the prefetch overwrites it)
#pragma unroll
        for (int t = 0; t < 2; ++t) {
            const unsigned m = smw[sl][t];
            acc[t][0] = (m & 0x000000FFu) ? acc[t][0] : 0.f;
            acc[t][1] = (m & 0x0000FF00u) ? acc[t][1] : 0.f;
            acc[t][2] = (m & 0x00FF0000u) ? acc[t][2] : 0.f;
            acc[t][3] = (m & 0xFF000000u) ? acc[t][3] : 0.f;
        }

        // prefetch iteration n+2 into slot sl — issued BEFORE this
        // iteration's stores so no future load-wait ever drains a store
        if (n + 2 < 16) {
            sa0[sl] = *(const bf16x8*)(pa0 + (size_t)(n + 2) * 16 * D);
            sa1[sl] = *(const bf16x8*)(pa0 + (size_t)(n + 2) * 16 * D + 32);
#pragma unroll
            for (int t = 0; t < 2; ++t)
                smw[sl][t] = *(const unsigned*)(pm0 + (size_t)(n + 2) * 16 * S + t * 16);
        }

        // stores: 2 x f32x4 (64B per row-segment), youngest vmem ops,
        // nontemporal -> don't churn L2 with write-once output
#pragma unroll
        for (int t = 0; t < 2; ++t)
            __builtin_nontemporal_store(acc[t],
                (f32x4*)(po0 + (size_t)n * 16 * S + t * 16));
    }
}

// ---------------- fallback (ws too small): inline conversion -----------------
__global__ __launch_bounds__(256) void masked_mm_f32_kernel(
    const float* __restrict__ A,
    const float* __restrict__ B,
    const float* __restrict__ M,
    float* __restrict__ O) {

    const int bh   = blockIdx.z;
    const int bb   = bh >> 3;
    const int lane = threadIdx.x & 63;
    const int w    = threadIdx.x >> 6;
    const int r0 = blockIdx.y * 64 + w * 16;
    const int c0 = blockIdx.x * 256;
    const int rlane = lane & 15;
    const int kg    = lane >> 4;

    const float* __restrict__ Ab = A + (size_t)bh * S * D;
    const float* __restrict__ Bb = B + (size_t)bh * S * D;
    const float* __restrict__ Mb = M + (size_t)bb * S * S;
    float* __restrict__ Ob       = O + (size_t)bh * S * S;

    const float* pa = Ab + (size_t)(r0 + rlane) * D + kg * 8;
    f32x4 fa0 = *(const f32x4*)pa, fa1 = *(const f32x4*)(pa + 4);
    f32x4 fa2 = *(const f32x4*)(pa + 32), fa3 = *(const f32x4*)(pa + 36);
    bf16x8 af0, af1;
    af0[0]=f2bf(fa0[0]); af0[1]=f2bf(fa0[1]); af0[2]=f2bf(fa0[2]); af0[3]=f2bf(fa0[3]);
    af0[4]=f2bf(fa1[0]); af0[5]=f2bf(fa1[1]); af0[6]=f2bf(fa1[2]); af0[7]=f2bf(fa1[3]);
    af1[0]=f2bf(fa2[0]); af1[1]=f2bf(fa2[1]); af1[2]=f2bf(fa2[2]); af1[3]=f2bf(fa2[3]);
    af1[4]=f2bf(fa3[0]); af1[5]=f2bf(fa3[1]); af1[6]=f2bf(fa3[2]); af1[7]=f2bf(fa3[3]);

    const size_t rowbase = (size_t)(r0 + rlane) * S + c0;

#pragma unroll
    for (int t = 0; t < 16; ++t) {
        const float* pb = Bb + (size_t)(c0 + t * 16 + rlane) * D + kg * 8;
        f32x4 g0 = *(const f32x4*)pb, g1 = *(const f32x4*)(pb + 4);
        f32x4 g2 = *(const f32x4*)(pb + 32), g3 = *(const f32x4*)(pb + 36);
        bf16x8 b0, b1;
        b0[0]=f2bf(g0[0]); b0[1]=f2bf(g0[1]); b0[2]=f2bf(g0[2]); b0[3]=f2bf(g0[3]);
        b0[4]=f2bf(g1[0]); b0[5]=f2bf(g1[1]); b0[6]=f2bf(g1[2]); b0[7]=f2bf(g1[3]);
        b1[0]=f2bf(g2[0]); b1[1]=f2bf(g2[1]); b1[2]=f2bf(g2[2]); b1[3]=f2bf(g2[3]);
        b1[4]=f2bf(g3[0]); b1[5]=f2bf(g3[1]); b1[6]=f2bf(g3[2]); b1[7]=f2bf(g3[3]);
        f32x4 z = {0.f, 0.f, 0.f, 0.f};
        z = __builtin_amdgcn_mfma_f32_16x16x32_bf16(b0, af0, z, 0, 0, 0);
        z = __builtin_amdgcn_mfma_f32_16x16x32_bf16(b1, af1, z, 0, 0, 0);
        f32x4 mkv = *(const f32x4*)(Mb + rowbase + t * 16 + kg * 4);
        z[0] *= mkv[0]; z[1] *= mkv[1]; z[2] *= mkv[2]; z[3] *= mkv[3];
        *(f32x4*)(Ob + rowbase + t * 16 + kg * 4) = z;
    }
}

extern "C" void kernel_launch(void* const* d_in, const int* in_sizes, int n_in,
                              void* d_out, int out_size, void* d_ws, size_t ws_size,
                              hipStream_t stream) {
    const float* a = (const float*)d_in[0];
    const float* b = (const float*)d_in[1];
    const float* m = (const float*)d_in[2];
    float* o = (float*)d_out;

    dim3 block(256);

    const size_t ws_need = 2 * NELEM * sizeof(short) + NMASK;  // 8.4 + 8.4 MB
    if (ws_size >= ws_need) {
        short* a16 = (short*)d_ws;
        short* b16 = a16 + NELEM;
        unsigned char* m8 = (unsigned char*)(b16 + NELEM);
        hipLaunchKernelGGL(prep_kernel, dim3(6144), block, 0, stream, a, b, m, a16, b16, m8);
        // 8192 waves = 64 col-panels x 8 row-octants x 16 bh; 2048 blocks =
        // exactly one full-occupancy round at 8 blocks/CU
        hipLaunchKernelGGL(masked_mm_bf16_kernel, dim3(2048), block, 0, stream,
                           a16, b16, m8, o);
    } else {
        dim3 grid(S / 256, S / 64, 16);
        hipLaunchKernelGGL(masked_mm_f32_kernel, grid, block, 0, stream, a, b, m, o);
    }
}

// Round 16
// 79.426 us; speedup vs baseline: 1.1263x; 1.1263x over previous
//
#include <hip/hip_runtime.h>

// MaskedDenseMatMul: out[b,h,q,k] = (sum_d a[b,h,q,d]*b[b,h,k,d]) * mask[b,0,q,k]
// B=2 H=8 S=2048 D=64, fp32 in/out.  Memory-bound on the 256 MiB output write.
//
// FINAL (R12 configuration, 79.5us measured):
//  - fused prep: A,B fp32->bf16 + mask fp32->u8 (prep itself is at BW
//    roofline: ~80MB in ~11us)
//  - main: long-lived waves (wave = 64 cols x 256 rows), loop-invariant B
//    fragments (loaded once), depth-4 register staging of A+mask (prefetch
//    distance ~3.5 iters covers congested read latency), store-last loop
//    body (MFMA -> mask select -> prefetch(n+4) -> 4 nt stores): stores are
//    always the youngest vmem ops, so no load-wait ever drains them
//    (vmcnt is in-order on CDNA) -> sustained store flow
//  - __builtin_nontemporal_store: write-once output doesn't churn L2
//  - __launch_bounds__(256,4): 4 waves/SIMD at ~130 VGPR
//  Confirmed-win ledger: store-last (R8 +15%), long-lived/loop-invariant-B
//  (R10 +10%), nt+occupancy-pin (R12 +13%).  Refuted: burst width, stream
//  contiguity, fetch volume, shallow pipelines, fusion, XCD swizzle, 8 w/SIMD.

typedef __attribute__((ext_vector_type(8))) short bf16x8;
typedef __attribute__((ext_vector_type(4))) float f32x4;
typedef __attribute__((ext_vector_type(2))) unsigned int u32x2;

static constexpr int S = 2048;
static constexpr int D = 64;
static constexpr size_t NELEM = (size_t)16 * S * D;   // elems per A/B input
static constexpr size_t NMASK = (size_t)2 * S * S;    // mask elems (B*S*S)

__device__ inline short f2bf(float f) {
    union { float f; unsigned u; } v; v.f = f;
    unsigned r = (v.u + 0x7FFFu + ((v.u >> 16) & 1u)) >> 16;
    return (short)r;
}

// ------------- fused pre-pass: cvt A (1024 blk), cvt B (1024), pack mask (4096)
__global__ __launch_bounds__(256) void prep_kernel(const float* __restrict__ a,
                                                   const float* __restrict__ b,
                                                   const float* __restrict__ m,
                                                   short* __restrict__ a16,
                                                   short* __restrict__ b16,
                                                   unsigned char* __restrict__ m8) {
    const int blk = blockIdx.x;
    if (blk < 2048) {
        const float* src = (blk < 1024) ? a : b;
        short* dst       = (blk < 1024) ? a16 : b16;
        size_t i = ((size_t)(blk & 1023) * 256 + threadIdx.x) * 8;
        f32x4 f0 = *(const f32x4*)(src + i);
        f32x4 f1 = *(const f32x4*)(src + i + 4);
        bf16x8 t;
        t[0] = f2bf(f0[0]); t[1] = f2bf(f0[1]); t[2] = f2bf(f0[2]); t[3] = f2bf(f0[3]);
        t[4] = f2bf(f1[0]); t[5] = f2bf(f1[1]); t[6] = f2bf(f1[2]); t[7] = f2bf(f1[3]);
        *(bf16x8*)(dst + i) = t;
    } else {
        size_t i = ((size_t)(blk - 2048) * 256 + threadIdx.x) * 8;
        f32x4 f0 = *(const f32x4*)(m + i);
        f32x4 f1 = *(const f32x4*)(m + i + 4);
        unsigned w0 = 0, w1 = 0;
        w0 |= (f0[0] != 0.f ? 1u : 0u);
        w0 |= (f0[1] != 0.f ? 1u : 0u) << 8;
        w0 |= (f0[2] != 0.f ? 1u : 0u) << 16;
        w0 |= (f0[3] != 0.f ? 1u : 0u) << 24;
        w1 |= (f1[0] != 0.f ? 1u : 0u);
        w1 |= (f1[1] != 0.f ? 1u : 0u) << 8;
        w1 |= (f1[2] != 0.f ? 1u : 0u) << 16;
        w1 |= (f1[3] != 0.f ? 1u : 0u) << 24;
        u32x2 w; w[0] = w0; w[1] = w1;
        *(u32x2*)(m8 + i) = w;
    }
}

// ------------- main kernel: loop-invariant B, depth-4 prefetch, nt stores ----
__global__ __launch_bounds__(256, 4) void masked_mm_bf16_kernel(
    const short* __restrict__ A16,
    const short* __restrict__ B16,
    const unsigned char* __restrict__ M8,
    float* __restrict__ O) {

    const int lane  = threadIdx.x & 63;
    const int rlane = lane & 15;              // MFMA operand row within 16
    const int kg    = lane >> 4;              // k-group 0..3

    // global wave id -> (col panel, row octant, bh); the 4 waves of a block
    // share (ro,bh) -> identical A reads (L1/L2 hits), adjacent col panels;
    // consecutive blocks extend one dense concurrent write band
    const int gw = blockIdx.x * 4 + (threadIdx.x >> 6);  // 0..4095
    const int cp = gw & 31;                   // 32 col panels of 64
    const int ro = (gw >> 5) & 7;             // 8 row octants of 256
    const int bh = gw >> 8;                   // 0..15
    const int bb = bh >> 3;

    const int c0 = cp * 64;
    const int r0 = ro * 256;

    const short* __restrict__ Ab = A16 + (size_t)bh * S * D;
    const short* __restrict__ Bb = B16 + (size_t)bh * S * D;
    const unsigned char* __restrict__ Mb = M8 + (size_t)bb * S * S;
    float* __restrict__ Ob       = O + (size_t)bh * S * S;

    // ---- loop-invariant B fragments: 4 tiles x (2 x K=32) = 32 VGPR ----
    bf16x8 bs0[4], bs1[4];
#pragma unroll
    for (int t = 0; t < 4; ++t) {
        const short* pb = Bb + (size_t)(c0 + t * 16 + rlane) * D + kg * 8;
        bs0[t] = *(const bf16x8*)(pb);
        bs1[t] = *(const bf16x8*)(pb + 32);
    }

    // ---- per-lane base pointers (advance by 16 rows per iteration) ----
    const short*         pa0 = Ab + (size_t)(r0 + rlane) * D + kg * 8;
    const unsigned char* pm0 = Mb + (size_t)(r0 + rlane) * S + c0 + kg * 4;
    float*               po0 = Ob + (size_t)(r0 + rlane) * S + c0 + kg * 4;

    // ---- depth-4 register staging (A frags + mask words) ----
    bf16x8   sa0[4], sa1[4];
    unsigned smw[4][4];
#pragma unroll
    for (int n = 0; n < 4; ++n) {
        sa0[n] = *(const bf16x8*)(pa0 + (size_t)n * 16 * D);
        sa1[n] = *(const bf16x8*)(pa0 + (size_t)n * 16 * D + 32);
#pragma unroll
        for (int t = 0; t < 4; ++t)
            smw[n][t] = *(const unsigned*)(pm0 + (size_t)n * 16 * S + t * 16);
    }

    // ---- main loop: 16 row-groups, fully unrolled (static slot indices) ----
#pragma unroll
    for (int n = 0; n < 16; ++n) {
        const int sl = n & 3;

        // MFMA (swapped operands: acc[t][j] = O[r0+n*16+rlane][c0+t*16+kg*4+j])
        f32x4 acc[4];
#pragma unroll
        for (int t = 0; t < 4; ++t) {
            f32x4 z = {0.f, 0.f, 0.f, 0.f};
            z = __builtin_amdgcn_mfma_f32_16x16x32_bf16(bs0[t], sa0[sl], z, 0, 0, 0);
            z = __builtin_amdgcn_mfma_f32_16x16x32_bf16(bs1[t], sa1[sl], z, 0, 0, 0);
            acc[t] = z;
        }

        // mask select (consumes smw[sl] before the prefetch overwrites it)
#pragma unroll
        for (int t = 0; t < 4; ++t) {
            const unsigned m = smw[sl][t];
            acc[t][0] = (m & 0x000000FFu) ? acc[t][0] : 0.f;
            acc[t][1] = (m & 0x0000FF00u) ? acc[t][1] : 0.f;
            acc[t][2] = (m & 0x00FF0000u) ? acc[t][2] : 0.f;
            acc[t][3] = (m & 0xFF000000u) ? acc[t][3] : 0.f;
        }

        // prefetch iteration n+4 into slot sl — issued BEFORE this
        // iteration's stores so no future load-wait ever drains a store
        if (n + 4 < 16) {
            sa0[sl] = *(const bf16x8*)(pa0 + (size_t)(n + 4) * 16 * D);
            sa1[sl] = *(const bf16x8*)(pa0 + (size_t)(n + 4) * 16 * D + 32);
#pragma unroll
            for (int t = 0; t < 4; ++t)
                smw[sl][t] = *(const unsigned*)(pm0 + (size_t)(n + 4) * 16 * S + t * 16);
        }

        // stores: 4 x f32x4 (64B per row-segment), youngest vmem ops,
        // nontemporal -> don't churn L2 with write-once output
#pragma unroll
        for (int t = 0; t < 4; ++t)
            __builtin_nontemporal_store(acc[t],
                (f32x4*)(po0 + (size_t)n * 16 * S + t * 16));
    }
}

// ---------------- fallback (ws too small): inline conversion -----------------
__global__ __launch_bounds__(256) void masked_mm_f32_kernel(
    const float* __restrict__ A,
    const float* __restrict__ B,
    const float* __restrict__ M,
    float* __restrict__ O) {

    const int bh   = blockIdx.z;
    const int bb   = bh >> 3;
    const int lane = threadIdx.x & 63;
    const int w    = threadIdx.x >> 6;
    const int r0 = blockIdx.y * 64 + w * 16;
    const int c0 = blockIdx.x * 256;
    const int rlane = lane & 15;
    const int kg    = lane >> 4;

    const float* __restrict__ Ab = A + (size_t)bh * S * D;
    const float* __restrict__ Bb = B + (size_t)bh * S * D;
    const float* __restrict__ Mb = M + (size_t)bb * S * S;
    float* __restrict__ Ob       = O + (size_t)bh * S * S;

    const float* pa = Ab + (size_t)(r0 + rlane) * D + kg * 8;
    f32x4 fa0 = *(const f32x4*)pa, fa1 = *(const f32x4*)(pa + 4);
    f32x4 fa2 = *(const f32x4*)(pa + 32), fa3 = *(const f32x4*)(pa + 36);
    bf16x8 af0, af1;
    af0[0]=f2bf(fa0[0]); af0[1]=f2bf(fa0[1]); af0[2]=f2bf(fa0[2]); af0[3]=f2bf(fa0[3]);
    af0[4]=f2bf(fa1[0]); af0[5]=f2bf(fa1[1]); af0[6]=f2bf(fa1[2]); af0[7]=f2bf(fa1[3]);
    af1[0]=f2bf(fa2[0]); af1[1]=f2bf(fa2[1]); af1[2]=f2bf(fa2[2]); af1[3]=f2bf(fa2[3]);
    af1[4]=f2bf(fa3[0]); af1[5]=f2bf(fa3[1]); af1[6]=f2bf(fa3[2]); af1[7]=f2bf(fa3[3]);

    const size_t rowbase = (size_t)(r0 + rlane) * S + c0;

#pragma unroll
    for (int t = 0; t < 16; ++t) {
        const float* pb = Bb + (size_t)(c0 + t * 16 + rlane) * D + kg * 8;
        f32x4 g0 = *(const f32x4*)pb, g1 = *(const f32x4*)(pb + 4);
        f32x4 g2 = *(const f32x4*)(pb + 32), g3 = *(const f32x4*)(pb + 36);
        bf16x8 b0, b1;
        b0[0]=f2bf(g0[0]); b0[1]=f2bf(g0[1]); b0[2]=f2bf(g0[2]); b0[3]=f2bf(g0[3]);
        b0[4]=f2bf(g1[0]); b0[5]=f2bf(g1[1]); b0[6]=f2bf(g1[2]); b0[7]=f2bf(g1[3]);
        b1[0]=f2bf(g2[0]); b1[1]=f2bf(g2[1]); b1[2]=f2bf(g2[2]); b1[3]=f2bf(g2[3]);
        b1[4]=f2bf(g3[0]); b1[5]=f2bf(g3[1]); b1[6]=f2bf(g3[2]); b1[7]=f2bf(g3[3]);
        f32x4 z = {0.f, 0.f, 0.f, 0.f};
        z = __builtin_amdgcn_mfma_f32_16x16x32_bf16(b0, af0, z, 0, 0, 0);
        z = __builtin_amdgcn_mfma_f32_16x16x32_bf16(b1, af1, z, 0, 0, 0);
        f32x4 mkv = *(const f32x4*)(Mb + rowbase + t * 16 + kg * 4);
        z[0] *= mkv[0]; z[1] *= mkv[1]; z[2] *= mkv[2]; z[3] *= mkv[3];
        *(f32x4*)(Ob + rowbase + t * 16 + kg * 4) = z;
    }
}

extern "C" void kernel_launch(void* const* d_in, const int* in_sizes, int n_in,
                              void* d_out, int out_size, void* d_ws, size_t ws_size,
                              hipStream_t stream) {
    const float* a = (const float*)d_in[0];
    const float* b = (const float*)d_in[1];
    const float* m = (const float*)d_in[2];
    float* o = (float*)d_out;

    dim3 block(256);

    const size_t ws_need = 2 * NELEM * sizeof(short) + NMASK;  // 8.4 + 8.4 MB
    if (ws_size >= ws_need) {
        short* a16 = (short*)d_ws;
        short* b16 = a16 + NELEM;
        unsigned char* m8 = (unsigned char*)(b16 + NELEM);
        hipLaunchKernelGGL(prep_kernel, dim3(6144), block, 0, stream, a, b, m, a16, b16, m8);
        // 4096 waves = 32 col-panels x 8 row-octants x 16 bh; 1024 blocks
        hipLaunchKernelGGL(masked_mm_bf16_kernel, dim3(1024), block, 0, stream,
                           a16, b16, m8, o);
    } else {
        dim3 grid(S / 256, S / 64, 16);
        hipLaunchKernelGGL(masked_mm_f32_kernel, grid, block, 0, stream, a, b, m, o);
    }
}

// Round 17
// 72.073 us; speedup vs baseline: 1.2412x; 1.1020x over previous
//
#include <hip/hip_runtime.h>

// MaskedDenseMatMul: out[b,h,q,k] = (sum_d a[b,h,q,d]*b[b,h,k,d]) * mask[b,0,q,k]
// B=2 H=8 S=2048 D=64, fp32 in/out.  Memory-bound on the 256 MiB output write.
//
// R17 design — producer/consumer wave specialization:
//  R12/R16 (79.5us) still mixes loads+stores in every wave's in-order vmcnt
//  FIFO; read-waits gate store issue.  Here each block's 4 waves split:
//   - waves 0,1 (PRODUCERS): global LOADS only.  Loop-invariant B frags,
//     depth-4 A+mask staging (R12's proven producer side), 8 MFMA, mask
//     select, ds_write to double-buffered LDS, s_waitcnt lgkmcnt(0) (asm),
//     raw s_barrier (NO vmcnt drain — __builtin, not __syncthreads).
//   - waves 2,3 (CONSUMERS): ZERO global loads ever.  barrier -> ds_read ->
//     nontemporal stores.  Their vmcnt FIFO contains only stores -> never
//     drained by any wait: the fill-kernel regime (7 TB/s @ 10% occ) exactly.
//  One barrier per iteration, both roles hit exactly 32 barriers; overlap is
//  natural: after barrier n, producer computes group n+1 while consumer
//  stores group n.  Double buffer makes the write of n+2 safe vs reads of n.
//  Block = 128 cols x 512 rows (32 iters of 16 rows); grid 1024 = 16 col
//  panels x 4 row quarters x 16 bh; consecutive blocks = adjacent col panels
//  (dense concurrent write band).  LDS 16.9KB, 4 blocks/CU.

typedef __attribute__((ext_vector_type(8))) short bf16x8;
typedef __attribute__((ext_vector_type(4))) float f32x4;
typedef __attribute__((ext_vector_type(2))) unsigned int u32x2;

static constexpr int S = 2048;
static constexpr int D = 64;
static constexpr size_t NELEM = (size_t)16 * S * D;   // elems per A/B input
static constexpr size_t NMASK = (size_t)2 * S * S;    // mask elems (B*S*S)
static constexpr int LR = 132;                        // LDS row stride (16B-aligned pad)

__device__ inline short f2bf(float f) {
    union { float f; unsigned u; } v; v.f = f;
    unsigned r = (v.u + 0x7FFFu + ((v.u >> 16) & 1u)) >> 16;
    return (short)r;
}

// ------------- fused pre-pass: cvt A (1024 blk), cvt B (1024), pack mask (4096)
__global__ __launch_bounds__(256) void prep_kernel(const float* __restrict__ a,
                                                   const float* __restrict__ b,
                                                   const float* __restrict__ m,
                                                   short* __restrict__ a16,
                                                   short* __restrict__ b16,
                                                   unsigned char* __restrict__ m8) {
    const int blk = blockIdx.x;
    if (blk < 2048) {
        const float* src = (blk < 1024) ? a : b;
        short* dst       = (blk < 1024) ? a16 : b16;
        size_t i = ((size_t)(blk & 1023) * 256 + threadIdx.x) * 8;
        f32x4 f0 = *(const f32x4*)(src + i);
        f32x4 f1 = *(const f32x4*)(src + i + 4);
        bf16x8 t;
        t[0] = f2bf(f0[0]); t[1] = f2bf(f0[1]); t[2] = f2bf(f0[2]); t[3] = f2bf(f0[3]);
        t[4] = f2bf(f1[0]); t[5] = f2bf(f1[1]); t[6] = f2bf(f1[2]); t[7] = f2bf(f1[3]);
        *(bf16x8*)(dst + i) = t;
    } else {
        size_t i = ((size_t)(blk - 2048) * 256 + threadIdx.x) * 8;
        f32x4 f0 = *(const f32x4*)(m + i);
        f32x4 f1 = *(const f32x4*)(m + i + 4);
        unsigned w0 = 0, w1 = 0;
        w0 |= (f0[0] != 0.f ? 1u : 0u);
        w0 |= (f0[1] != 0.f ? 1u : 0u) << 8;
        w0 |= (f0[2] != 0.f ? 1u : 0u) << 16;
        w0 |= (f0[3] != 0.f ? 1u : 0u) << 24;
        w1 |= (f1[0] != 0.f ? 1u : 0u);
        w1 |= (f1[1] != 0.f ? 1u : 0u) << 8;
        w1 |= (f1[2] != 0.f ? 1u : 0u) << 16;
        w1 |= (f1[3] != 0.f ? 1u : 0u) << 24;
        u32x2 w; w[0] = w0; w[1] = w1;
        *(u32x2*)(m8 + i) = w;
    }
}

// ------------- main kernel: producer/consumer wave specialization ------------
__global__ __launch_bounds__(256, 4) void masked_mm_pc_kernel(
    const short* __restrict__ A16,
    const short* __restrict__ B16,
    const unsigned char* __restrict__ M8,
    float* __restrict__ O) {

    __shared__ float lds[2][16][LR];          // 16896 B double buffer

    const int lane = threadIdx.x & 63;
    const int w    = threadIdx.x >> 6;        // 0,1 producers; 2,3 consumers

    const int gw = blockIdx.x;                // 0..1023
    const int cp = gw & 15;                   // 16 col panels of 128
    const int rq = (gw >> 4) & 3;             // 4 row quarters of 512
    const int bh = gw >> 6;                   // 0..15
    const int bb = bh >> 3;

    const int c0 = cp * 128;
    const int r0 = rq * 512;

    const short* __restrict__ Ab = A16 + (size_t)bh * S * D;
    const short* __restrict__ Bb = B16 + (size_t)bh * S * D;
    const unsigned char* __restrict__ Mb = M8 + (size_t)bb * S * S;
    float* __restrict__ Ob       = O + (size_t)bh * S * S;

    if (w < 2) {
        // ================= PRODUCER (global loads only) =================
        const int rlane = lane & 15;          // MFMA operand row within 16
        const int kg    = lane >> 4;          // k-group 0..3
        const int wc0   = c0 + w * 64;        // this producer's 64 cols

        // loop-invariant B fragments: 4 tiles x (2 x K=32) = 32 VGPR
        bf16x8 bs0[4], bs1[4];
#pragma unroll
        for (int t = 0; t < 4; ++t) {
            const short* pb = Bb + (size_t)(wc0 + t * 16 + rlane) * D + kg * 8;
            bs0[t] = *(const bf16x8*)(pb);
            bs1[t] = *(const bf16x8*)(pb + 32);
        }

        const short*         pa0 = Ab + (size_t)(r0 + rlane) * D + kg * 8;
        const unsigned char* pm0 = Mb + (size_t)(r0 + rlane) * S + wc0 + kg * 4;

        // depth-4 register staging (A frags + mask words) — R12's recipe
        bf16x8   sa0[4], sa1[4];
        unsigned smw[4][4];
#pragma unroll
        for (int n = 0; n < 4; ++n) {
            sa0[n] = *(const bf16x8*)(pa0 + (size_t)n * 16 * D);
            sa1[n] = *(const bf16x8*)(pa0 + (size_t)n * 16 * D + 32);
#pragma unroll
            for (int t = 0; t < 4; ++t)
                smw[n][t] = *(const unsigned*)(pm0 + (size_t)n * 16 * S + t * 16);
        }

#pragma unroll
        for (int n = 0; n < 32; ++n) {
            const int sl = n & 3;

            f32x4 acc[4];
#pragma unroll
            for (int t = 0; t < 4; ++t) {
                f32x4 z = {0.f, 0.f, 0.f, 0.f};
                z = __builtin_amdgcn_mfma_f32_16x16x32_bf16(bs0[t], sa0[sl], z, 0, 0, 0);
                z = __builtin_amdgcn_mfma_f32_16x16x32_bf16(bs1[t], sa1[sl], z, 0, 0, 0);
                acc[t] = z;
            }

            // mask select (producer applies mask so consumer is pure copy)
#pragma unroll
            for (int t = 0; t < 4; ++t) {
                const unsigned m = smw[sl][t];
                acc[t][0] = (m & 0x000000FFu) ? acc[t][0] : 0.f;
                acc[t][1] = (m & 0x0000FF00u) ? acc[t][1] : 0.f;
                acc[t][2] = (m & 0x00FF0000u) ? acc[t][2] : 0.f;
                acc[t][3] = (m & 0xFF000000u) ? acc[t][3] : 0.f;
            }

            // prefetch n+4 (loads only — producer never stores to global)
            if (n + 4 < 32) {
                sa0[sl] = *(const bf16x8*)(pa0 + (size_t)(n + 4) * 16 * D);
                sa1[sl] = *(const bf16x8*)(pa0 + (size_t)(n + 4) * 16 * D + 32);
#pragma unroll
                for (int t = 0; t < 4; ++t)
                    smw[sl][t] = *(const unsigned*)(pm0 + (size_t)(n + 4) * 16 * S + t * 16);
            }

            // publish group n to the double buffer
#pragma unroll
            for (int t = 0; t < 4; ++t)
                *(f32x4*)&lds[n & 1][rlane][w * 64 + t * 16 + kg * 4] = acc[t];

            asm volatile("s_waitcnt lgkmcnt(0)" ::: "memory");
            __builtin_amdgcn_s_barrier();
        }
    } else {
        // ================= CONSUMER (global stores only) =================
        const int cw  = w - 2;                // 0,1 -> rows 0-7 / 8-15
        const int h2  = lane >> 5;            // row within pair
        const int c32 = lane & 31;            // col/4 within 128-col panel

#pragma unroll
        for (int n = 0; n < 32; ++n) {
            __builtin_amdgcn_s_barrier();
            asm volatile("" ::: "memory");    // no ds_read hoist above barrier

#pragma unroll
            for (int p = 0; p < 4; ++p) {
                const int rr = cw * 8 + 2 * p + h2;
                f32x4 v = *(const f32x4*)&lds[n & 1][rr][c32 * 4];
                __builtin_nontemporal_store(v,
                    (f32x4*)(Ob + (size_t)(r0 + n * 16 + rr) * S + c0 + c32 * 4));
            }
        }
    }
}

// ---------------- fallback (ws too small): inline conversion -----------------
__global__ __launch_bounds__(256) void masked_mm_f32_kernel(
    const float* __restrict__ A,
    const float* __restrict__ B,
    const float* __restrict__ M,
    float* __restrict__ O) {

    const int bh   = blockIdx.z;
    const int bb   = bh >> 3;
    const int lane = threadIdx.x & 63;
    const int w    = threadIdx.x >> 6;
    const int r0 = blockIdx.y * 64 + w * 16;
    const int c0 = blockIdx.x * 256;
    const int rlane = lane & 15;
    const int kg    = lane >> 4;

    const float* __restrict__ Ab = A + (size_t)bh * S * D;
    const float* __restrict__ Bb = B + (size_t)bh * S * D;
    const float* __restrict__ Mb = M + (size_t)bb * S * S;
    float* __restrict__ Ob       = O + (size_t)bh * S * S;

    const float* pa = Ab + (size_t)(r0 + rlane) * D + kg * 8;
    f32x4 fa0 = *(const f32x4*)pa, fa1 = *(const f32x4*)(pa + 4);
    f32x4 fa2 = *(const f32x4*)(pa + 32), fa3 = *(const f32x4*)(pa + 36);
    bf16x8 af0, af1;
    af0[0]=f2bf(fa0[0]); af0[1]=f2bf(fa0[1]); af0[2]=f2bf(fa0[2]); af0[3]=f2bf(fa0[3]);
    af0[4]=f2bf(fa1[0]); af0[5]=f2bf(fa1[1]); af0[6]=f2bf(fa1[2]); af0[7]=f2bf(fa1[3]);
    af1[0]=f2bf(fa2[0]); af1[1]=f2bf(fa2[1]); af1[2]=f2bf(fa2[2]); af1[3]=f2bf(fa2[3]);
    af1[4]=f2bf(fa3[0]); af1[5]=f2bf(fa3[1]); af1[6]=f2bf(fa3[2]); af1[7]=f2bf(fa3[3]);

    const size_t rowbase = (size_t)(r0 + rlane) * S + c0;

#pragma unroll
    for (int t = 0; t < 16; ++t) {
        const float* pb = Bb + (size_t)(c0 + t * 16 + rlane) * D + kg * 8;
        f32x4 g0 = *(const f32x4*)pb, g1 = *(const f32x4*)(pb + 4);
        f32x4 g2 = *(const f32x4*)(pb + 32), g3 = *(const f32x4*)(pb + 36);
        bf16x8 b0, b1;
        b0[0]=f2bf(g0[0]); b0[1]=f2bf(g0[1]); b0[2]=f2bf(g0[2]); b0[3]=f2bf(g0[3]);
        b0[4]=f2bf(g1[0]); b0[5]=f2bf(g1[1]); b0[6]=f2bf(g1[2]); b0[7]=f2bf(g1[3]);
        b1[0]=f2bf(g2[0]); b1[1]=f2bf(g2[1]); b1[2]=f2bf(g2[2]); b1[3]=f2bf(g2[3]);
        b1[4]=f2bf(g3[0]); b1[5]=f2bf(g3[1]); b1[6]=f2bf(g3[2]); b1[7]=f2bf(g3[3]);
        f32x4 z = {0.f, 0.f, 0.f, 0.f};
        z = __builtin_amdgcn_mfma_f32_16x16x32_bf16(b0, af0, z, 0, 0, 0);
        z = __builtin_amdgcn_mfma_f32_16x16x32_bf16(b1, af1, z, 0, 0, 0);
        f32x4 mkv = *(const f32x4*)(Mb + rowbase + t * 16 + kg * 4);
        z[0] *= mkv[0]; z[1] *= mkv[1]; z[2] *= mkv[2]; z[3] *= mkv[3];
        *(f32x4*)(Ob + rowbase + t * 16 + kg * 4) = z;
    }
}

extern "C" void kernel_launch(void* const* d_in, const int* in_sizes, int n_in,
                              void* d_out, int out_size, void* d_ws, size_t ws_size,
                              hipStream_t stream) {
    const float* a = (const float*)d_in[0];
    const float* b = (const float*)d_in[1];
    const float* m = (const float*)d_in[2];
    float* o = (float*)d_out;

    dim3 block(256);

    const size_t ws_need = 2 * NELEM * sizeof(short) + NMASK;  // 8.4 + 8.4 MB
    if (ws_size >= ws_need) {
        short* a16 = (short*)d_ws;
        short* b16 = a16 + NELEM;
        unsigned char* m8 = (unsigned char*)(b16 + NELEM);
        hipLaunchKernelGGL(prep_kernel, dim3(6144), block, 0, stream, a, b, m, a16, b16, m8);
        // 1024 blocks = 16 col panels x 4 row quarters x 16 bh
        hipLaunchKernelGGL(masked_mm_pc_kernel, dim3(1024), block, 0, stream,
                           a16, b16, m8, o);
    } else {
        dim3 grid(S / 256, S / 64, 16);
        hipLaunchKernelGGL(masked_mm_f32_kernel, grid, block, 0, stream, a, b, m, o);
    }
}